// Round 19
// baseline (126.632 us; speedup 1.0000x reference)
//
#include <hip/hip_runtime.h>
#include <hip/hip_bf16.h>
#include <cstdint>

// Problem: B=32, T1=T2=512, D=128, gamma=1.0
// out[b] = softDTW( 1 - cos_sim(x[b], y[b]) )
//
// ws layout:
//   skew : 32*1023*512 floats = 16,760,832   (cost/ln2, anti-diagonal layout)
//   xnb  : 32*512*128 bf16 (as 1,048,576 uints)
//   ynb  : same

#define BT      32
#define TLEN    512
#define DF      128
#define NDIAG   1023          // kd = 0..1022
#define BIGV    1e30f
#define INV_LN2 1.44269504088896340f
#define LN2     0.69314718055994531f

typedef short bf16x8 __attribute__((ext_vector_type(8)));
typedef float f32x4  __attribute__((ext_vector_type(4)));

__device__ __forceinline__ unsigned f2bf(float f) {     // RNE f32 -> bf16 bits
    unsigned u = __builtin_bit_cast(unsigned, f);
    return (u + 0x7FFFu + ((u >> 16) & 1u)) >> 16;
}

// ---------------------------------------------- normalize + cast to bf16
__global__ __launch_bounds__(256) void sdtw_normcast(const float* __restrict__ x,
                                                     const float* __restrict__ y,
                                                     unsigned* __restrict__ ox,
                                                     unsigned* __restrict__ oy) {
    const float* in  = blockIdx.y ? y : x;
    unsigned*    out = blockIdx.y ? oy : ox;
    int row = blockIdx.x * 4 + (threadIdx.x >> 6);
    int t   = threadIdx.x & 63;
    float2 v = reinterpret_cast<const float2*>(in + (size_t)row * DF)[t];
    float s = v.x * v.x + v.y * v.y;
    #pragma unroll
    for (int o = 32; o; o >>= 1) s += __shfl_xor(s, o);
    float scale = 1.0f / fmaxf(sqrtf(s), 1e-12f);
    out[(size_t)row * 64 + t] = f2bf(v.x * scale) | (f2bf(v.y * scale) << 16);
}

// ---------------------------------------------- bf16 MFMA GEMM -> skew (R18)
#define LDSTRIDE 272                         // bytes per LDS row (136 bf16)

__global__ __launch_bounds__(256) void sdtw_gemm_skew(const unsigned* __restrict__ xnb,
                                                      const unsigned* __restrict__ ynb,
                                                      float* __restrict__ skew) {
    __shared__ short smem[34816];            // 69,632 B: A + B
    char* As = (char*)smem;
    char* Bs = (char*)smem + 34816;

    const int b  = blockIdx.z;
    const int r0 = blockIdx.y * 128;
    const int c0 = blockIdx.x * 128;
    const int tid = threadIdx.x;
    const int wid = tid >> 6, l = tid & 63;
    const int lr = l & 15, lg = l >> 4;

    const char* xg = (const char*)(xnb + ((size_t)b * TLEN + r0) * 64);
    const char* yg = (const char*)(ynb + ((size_t)b * TLEN + c0) * 64);

    #pragma unroll
    for (int p = 0; p < 8; ++p) {
        int idx = p * 256 + tid;
        int row = idx >> 4, u = idx & 15;
        *(uint4*)(As + row * LDSTRIDE + u * 16) = *(const uint4*)(xg + row * 256 + u * 16);
        *(uint4*)(Bs + row * LDSTRIDE + u * 16) = *(const uint4*)(yg + row * 256 + u * 16);
    }
    __syncthreads();

    f32x4 acc[8][2];
    #pragma unroll
    for (int rt = 0; rt < 8; ++rt)
        #pragma unroll
        for (int ct = 0; ct < 2; ++ct) acc[rt][ct] = (f32x4){0.f, 0.f, 0.f, 0.f};

    #pragma unroll
    for (int kb = 0; kb < 4; ++kb) {
        bf16x8 af[8], bfr[2];
        #pragma unroll
        for (int rt = 0; rt < 8; ++rt)
            af[rt] = *(const bf16x8*)(As + (rt * 16 + lr) * LDSTRIDE + kb * 64 + lg * 16);
        #pragma unroll
        for (int ct = 0; ct < 2; ++ct)
            bfr[ct] = *(const bf16x8*)(Bs + (wid * 32 + ct * 16 + lr) * LDSTRIDE + kb * 64 + lg * 16);
        #pragma unroll
        for (int rt = 0; rt < 8; ++rt)
            #pragma unroll
            for (int ct = 0; ct < 2; ++ct)
                acc[rt][ct] = __builtin_amdgcn_mfma_f32_16x16x32_bf16(af[rt], bfr[ct], acc[rt][ct], 0, 0, 0);
    }

    __syncthreads();
    float* cs = (float*)smem;                // [128][130]
    #pragma unroll
    for (int rt = 0; rt < 8; ++rt)
        #pragma unroll
        for (int ct = 0; ct < 2; ++ct)
            #pragma unroll
            for (int r = 0; r < 4; ++r) {
                int row = rt * 16 + lg * 4 + r;
                int col = wid * 32 + ct * 16 + lr;
                cs[row * 130 + col] = (1.0f - acc[rt][ct][r]) * INV_LN2;
            }
    __syncthreads();

    float* sk = skew + (size_t)b * (NDIAG * TLEN);
    for (int dd = wid; dd < 255; dd += 4) {
        int lo = max(0, dd - 127), hi = min(127, dd);
        for (int rb = lo; rb <= hi; rb += 64) {
            int rl = rb + l;
            if (rl <= hi)
                sk[(size_t)(r0 + c0 + dd) * TLEN + r0 + rl] = cs[rl * 129 + dd];
        }
    }
}

// ----------------------------------------------------------------- DTW DP
// R19: segment length S = 32 (was 16). 39 segments (s=0..38), stagger = 1
// segment: chunk c handles diags kd0 = 32(s-c) + [0,31] at segment s.
// Active window aw = s-3c in [0,17]; warm-up aw==-1; INTERIOR aw in [2,15]
// (all cells valid: 32*2=64>=63, 32*15<=481); PARTIAL else. Ring deepened to
// 16 quads: consumer hoists slots q0..q0+7 (written by producer in seg s-1,
// barrier-separated); producer concurrently writes q0+8..q0+15 (disjoint
// mod 16). bd_up/dgs carry across the barrier covers diag kd0-1. Junk
// segments write 8 BIGV quads at the same slot formula (exactly the slots
// the consumer will hoist next segment). Prefetch ring c0..c7: phase t
// loads kd0+t+8; at seg end regs hold next seg's first 8 diags.
// Amortization: per-segment fixed overhead (~1300 cy: barrier convoy +
// hoist + prologue) paid 39x instead of 71x; fill grows 112->224 phases.

__device__ __forceinline__ int clampi(int v) {
    return v < 0 ? 0 : (v > NDIAG - 1 ? NDIAG - 1 : v);
}

__device__ __forceinline__ float dpp_shr1_old(float old, float x) {
    return __builtin_bit_cast(float,
        __builtin_amdgcn_update_dpp(__builtin_bit_cast(int, old),
                                    __builtin_bit_cast(int, x),
                                    0x138 /*wave_shr:1*/, 0xF, 0xF, false));
}

#define PH(s, CC, PN, PO, NQC, MASKED, CLAMPED)                                \
  {                                                                            \
    float up_ = dpp_shr1_old(bd_up, PN);     /* lane0 <- bd_up */              \
    float dg_ = dgs;                         /* patched up_ of prev phase */   \
    float m_   = fminf(fminf(dg_, PN), up_);                                   \
    float mid_ = __builtin_amdgcn_fmed3f(dg_, PN, up_);                        \
    float mx_  = fmaxf(fmaxf(dg_, PN), up_);                                   \
    float e_   = 1.0f + __builtin_amdgcn_exp2f(m_ - mid_)                      \
                      + __builtin_amdgcn_exp2f(m_ - mx_);                      \
    float v_   = CC + m_ - __builtin_amdgcn_logf(e_);                          \
    PO = (MASKED) ? (((unsigned)(vb0 + (s)) < 512u) ? v_ : vBig) : v_;         \
    if (((s) & 3) == 0) bq.x = PO;                                             \
    if (((s) & 3) == 1) bq.y = PO;                                             \
    if (((s) & 3) == 2) bq.z = PO;                                             \
    if (((s) & 3) == 3) { bq.w = PO;                                           \
      if (lt == 63) bnd4[c + 1][(q0 + ((s) >> 2)) & 15] = bq; }                \
    bd_up = (NQC);                                                             \
    dgs = up_;                                                                 \
    { int kl_ = kd0 + (s) + 8; if (CLAMPED) kl_ = clampi(kl_);                 \
      CC = skb[(size_t)kl_ * TLEN]; }                                          \
  }

#define SEG_BODY32(MASKED, CLAMPED)                                            \
    PH(0,  c0, P, Q, nq0.x, MASKED, CLAMPED) PH(1,  c1, Q, P, nq0.y, MASKED, CLAMPED) \
    PH(2,  c2, P, Q, nq0.z, MASKED, CLAMPED) PH(3,  c3, Q, P, nq0.w, MASKED, CLAMPED) \
    PH(4,  c4, P, Q, nq1.x, MASKED, CLAMPED) PH(5,  c5, Q, P, nq1.y, MASKED, CLAMPED) \
    PH(6,  c6, P, Q, nq1.z, MASKED, CLAMPED) PH(7,  c7, Q, P, nq1.w, MASKED, CLAMPED) \
    PH(8,  c0, P, Q, nq2.x, MASKED, CLAMPED) PH(9,  c1, Q, P, nq2.y, MASKED, CLAMPED) \
    PH(10, c2, P, Q, nq2.z, MASKED, CLAMPED) PH(11, c3, Q, P, nq2.w, MASKED, CLAMPED) \
    PH(12, c4, P, Q, nq3.x, MASKED, CLAMPED) PH(13, c5, Q, P, nq3.y, MASKED, CLAMPED) \
    PH(14, c6, P, Q, nq3.z, MASKED, CLAMPED) PH(15, c7, Q, P, nq3.w, MASKED, CLAMPED) \
    PH(16, c0, P, Q, nq4.x, MASKED, CLAMPED) PH(17, c1, Q, P, nq4.y, MASKED, CLAMPED) \
    PH(18, c2, P, Q, nq4.z, MASKED, CLAMPED) PH(19, c3, Q, P, nq4.w, MASKED, CLAMPED) \
    PH(20, c4, P, Q, nq5.x, MASKED, CLAMPED) PH(21, c5, Q, P, nq5.y, MASKED, CLAMPED) \
    PH(22, c6, P, Q, nq5.z, MASKED, CLAMPED) PH(23, c7, Q, P, nq5.w, MASKED, CLAMPED) \
    PH(24, c0, P, Q, nq6.x, MASKED, CLAMPED) PH(25, c1, Q, P, nq6.y, MASKED, CLAMPED) \
    PH(26, c2, P, Q, nq6.z, MASKED, CLAMPED) PH(27, c3, Q, P, nq6.w, MASKED, CLAMPED) \
    PH(28, c4, P, Q, nq7.x, MASKED, CLAMPED) PH(29, c5, Q, P, nq7.y, MASKED, CLAMPED) \
    PH(30, c6, P, Q, nq7.z, MASKED, CLAMPED) PH(31, c7, Q, P, nq7.w, MASKED, CLAMPED)

#define PRIME(K)                                                               \
    c0 = skb[(size_t)clampi((K) + 0) * TLEN];                                  \
    c1 = skb[(size_t)clampi((K) + 1) * TLEN];                                  \
    c2 = skb[(size_t)clampi((K) + 2) * TLEN];                                  \
    c3 = skb[(size_t)clampi((K) + 3) * TLEN];                                  \
    c4 = skb[(size_t)clampi((K) + 4) * TLEN];                                  \
    c5 = skb[(size_t)clampi((K) + 5) * TLEN];                                  \
    c6 = skb[(size_t)clampi((K) + 6) * TLEN];                                  \
    c7 = skb[(size_t)clampi((K) + 7) * TLEN];

__global__ __launch_bounds__(512) void sdtw_dp(const float* __restrict__ skew,
                                               float* __restrict__ out) {
    const int b   = blockIdx.x;
    const int tid = threadIdx.x;
    const int ww  = tid >> 6;                    // hardware wave id
    const int c   = ((ww & 3) << 1) | (ww >> 2); // chunk (SIMD-aware remap)
    const int lt  = tid & 63;
    const int row = 64 * c + lt;
    const float* skb = skew + (size_t)b * (NDIAG * TLEN) + row;

    __shared__ float4 bnd4[9][16];               // [consumer chunk][ring slot]
    if (tid < 512) { ((float*)bnd4)[tid] = BIGV; if (tid < 64) ((float*)bnd4)[512 + tid] = BIGV; }

    float P = BIGV, Q = BIGV;
    float vBig  = BIGV;
    float bd_up = BIGV;
    float dgs   = (tid == 0) ? 0.0f : BIGV;      // R(0,0)=0 at kd=0 (chunk0 lane0)
    float4 bq = make_float4(BIGV, BIGV, BIGV, BIGV);

    __syncthreads();

    float c0, c1, c2, c3, c4, c5, c6, c7;
    PRIME(-32 * c)                               // real for chunk 0; re-primed at warm-up

    for (int s = 0; s < 39; ++s) {
        const int aw  = s - 3 * c;               // wave-uniform window var
        const int kd0 = 32 * (s - c);
        const int q0  = (8 * (s - c)) & 15;      // first ring slot this segment
        const int vb0 = kd0 - row;

        if (aw >= -1 && aw <= 17) {
            // hoisted quads: written by producer during segment s-1 -> race-free
            float4 nq0 = bnd4[c][q0];
            float4 nq1 = bnd4[c][(q0 + 1) & 15];
            float4 nq2 = bnd4[c][(q0 + 2) & 15];
            float4 nq3 = bnd4[c][(q0 + 3) & 15];
            float4 nq4 = bnd4[c][(q0 + 4) & 15];
            float4 nq5 = bnd4[c][(q0 + 5) & 15];
            float4 nq6 = bnd4[c][(q0 + 6) & 15];
            float4 nq7 = bnd4[c][(q0 + 7) & 15];
            if (aw == -1) { PRIME(kd0) }         // warm-up: re-prime prefetch
            if (aw >= 2 && aw <= 15) { SEG_BODY32(0, 0) }   // interior
            else                     { SEG_BODY32(1, 1) }   // staircase/warm-up
        } else {
            if (lt == 63) {                      // junk: keep boundary cadence
                float4 bigq = make_float4(BIGV, BIGV, BIGV, BIGV);
                #pragma unroll
                for (int i = 0; i < 8; ++i)
                    bnd4[c + 1][(q0 + i) & 15] = bigq;
            }
        }
        __syncthreads();
    }

    if (tid == 511) out[b] = Q * LN2;            // chunk 7, row 511: R'(512,512)*ln2
}

// ---------------------------------------------------------------- launcher
extern "C" void kernel_launch(void* const* d_in, const int* in_sizes, int n_in,
                              void* d_out, int out_size, void* d_ws, size_t ws_size,
                              hipStream_t stream) {
    const float* x = (const float*)d_in[0];
    const float* y = (const float*)d_in[1];
    float* outp = (float*)d_out;

    float*    skew = (float*)d_ws;                        // 16,760,832 floats
    unsigned* xnb  = (unsigned*)(skew + (size_t)16760832);
    unsigned* ynb  = xnb + 1048576;

    sdtw_normcast<<<dim3(BT * TLEN / 4, 2), dim3(256), 0, stream>>>(x, y, xnb, ynb);
    sdtw_gemm_skew<<<dim3(4, 4, BT), dim3(256), 0, stream>>>(xnb, ynb, skew);
    sdtw_dp<<<dim3(BT), dim3(512), 0, stream>>>(skew, outp);
}